// Round 4
// baseline (174.145 us; speedup 1.0000x reference)
//
#include <hip/hip_runtime.h>
#include <cstdint>

#define N_ANCH 8400
#define CBLK 132              // ceil(8400/64)
#define SCORE_THR 0.5f

typedef unsigned long long u64;
typedef unsigned int u32;

// Sort key: ascending sort == (valid score descending, then index ascending,
// invalid last by index ascending) — exactly matches
// argsort(-where(valid, s, -inf)) with stable ties.
__device__ __forceinline__ u64 sort_key(float s, int idx) {
  u32 k32 = (s >= SCORE_THR) ? ~__float_as_uint(s) : 0xFFFFFFFFu;
  return ((u64)k32 << 32) | (u32)idx;
}

// Force a wave-uniform u64 into SGPRs.
__device__ __forceinline__ u64 rfl64(u64 v) {
  u32 lo = (u32)__builtin_amdgcn_readfirstlane((int)(u32)v);
  u32 hi = (u32)__builtin_amdgcn_readfirstlane((int)(u32)(v >> 32));
  return ((u64)hi << 32) | lo;
}

// One 64-lane wave per anchor: rank = #{keys smaller}, then scatter
// decoded box + score into sorted position.
__global__ void __launch_bounds__(256) rank_kernel(const float* __restrict__ raw,
                                                   float4* __restrict__ sbox,
                                                   float* __restrict__ sscore) {
  #pragma clang fp contract(off)
  int tid = blockIdx.x * 256 + threadIdx.x;
  int row = tid >> 6, lane = tid & 63;
  if (row >= N_ANCH) return;
  float si = raw[4 * N_ANCH + row];
  u64 ki = sort_key(si, row);
  int cnt = 0;
  for (int j = lane; j < N_ANCH; j += 64) {
    float sj = raw[4 * N_ANCH + j];
    cnt += (sort_key(sj, j) < ki) ? 1 : 0;
  }
  #pragma unroll
  for (int d = 1; d < 64; d <<= 1) cnt += __shfl_xor(cnt, d, 64);
  if (lane == 0) {
    float cx = raw[row], cy = raw[N_ANCH + row];
    float w = raw[2 * N_ANCH + row], h = raw[3 * N_ANCH + row];
    float hw = w * 0.5f, hh = h * 0.5f;
    sbox[cnt] = make_float4(cx - hw, cy - hh, cx + hw, cy + hh);
    sscore[cnt] = si;
  }
}

// Suppression bitmask over sorted boxes, BOTH triangles, one array:
//   cb > (i>>6)  (strictly above diagonal): wHi — bit jj set iff jg>i and
//                iou>0.5 (row word: "boxes I suppress"). Read by nms tiles.
//   cb <= (i>>6) (diagonal + below):        wLo — bit jj set iff jg<i and
//                iou>0.5 (COLUMN word: "boxes that suppress me"). Read by
//                nms wave0's ballot scan/carry.
// The two regions partition exactly what nms reads (tiles only touch
// cb >= rowblk+4; scan/carry only touch cb <= rowblk). Same IoU arithmetic
// as before — only the predicate selecting the bit differs.
__global__ void __launch_bounds__(256) mask_kernel(const float4* __restrict__ sbox,
                                                   const float* __restrict__ sscore,
                                                   u64* __restrict__ mask) {
  #pragma clang fp contract(off)
  int cb = blockIdx.x;
  int i0 = blockIdx.y * 256;
  if (!(sscore[i0] >= SCORE_THR)) return;        // whole row-block invalid
  if (!(sscore[cb * 64] >= SCORE_THR)) return;   // whole col-block invalid
  int t = threadIdx.x;
  __shared__ float4 cbox[64];
  __shared__ float carea[64];
  int j0 = cb * 64;
  if (t < 64) {
    int j = j0 + t;
    float4 bj = (j < N_ANCH) ? sbox[j] : make_float4(0.f, 0.f, 0.f, 0.f);
    cbox[t] = bj;
    carea[t] = (bj.z - bj.x) * (bj.w - bj.y);
  }
  __syncthreads();
  int i = i0 + t;
  if (i >= N_ANCH) return;
  float4 bi = sbox[i];
  float ai = (bi.z - bi.x) * (bi.w - bi.y);
  u64 wHi = 0, wLo = 0;
  for (int jj = 0; jj < 64; ++jj) {
    int jg = j0 + jj;
    float4 bb = cbox[jj];
    float ltx = fmaxf(bi.x, bb.x), lty = fmaxf(bi.y, bb.y);
    float rbx = fminf(bi.z, bb.z), rby = fminf(bi.w, bb.w);
    float wx = fmaxf(rbx - ltx, 0.f), wy = fmaxf(rby - lty, 0.f);
    float inter = wx * wy;
    float uni = (ai + carea[jj]) - inter;      // same op order as reference
    float iou = inter / fmaxf(uni, 1e-9f);     // IEEE div, matches numpy
    bool sup = (iou > 0.5f) && (jg < N_ANCH);
    wHi |= (u64)(sup && (jg > i)) << jj;
    wLo |= (u64)(sup && (jg < i)) << jj;
  }
  mask[(u64)i * CBLK + cb] = (cb > (i >> 6)) ? wHi : wLo;
}

// PIPELINED NMS with WAVE-PARALLEL BALLOT SCAN. 128 rows (words b0=2T,
// b1=2T+1) per iteration, ONE barrier per iteration. Wave 0 scans iter T
// while waves 1-7 apply iter T-1's keep-words to columns [2T+2, 2T+130).
//
// Scan: lane i holds COLUMN word c_i (suppressors of box i, all j<i by
// construction). Greedy fixpoint per word:
//   U=act; while(U){ covered=ballot(c&U); newK=U&~covered;
//                    supp=ballot(c&newK); K|=newK; U&=~(newK|supp); }
// Exact greedy: newK are boxes with NO remaining potential suppressor
// (suppressors in K already removed their victims; suppressors in "supp"
// never suppress), and >=1 box (min U) resolves per round. Rounds = depth
// of the suppression DAG (small), each ~2 ballots — replaces the serial
// one-keeper-per-trip readlane loop (~30 trips x ~70cy).
//
// Cross-word coupling (word0 keepers -> word1) is ONE ballot via cB.
// Carry (words b0,b1 -> cols b0+2,b0+3, closing the pipeline's 2-col gap)
// is TWO ballots via cD/cE — replaces the 12-step shfl butterfly.
// rem is a single LDS array updated with ds_or atomics by consume waves
// (cols >= 2T+2, disjoint from wave0's reads of b0,b1) — replaces the
// 7-array 14-read gather.
//
// Coverage: consume of words 2u,2u+1 (at iter u+1) spans cols [2u+4,2u+132)
// — max distance 131 covers VB<=132. Cols 2u+2,2u+3 come from the carry.
// Barriers drain LDS ONLY (lgkmcnt) — global prefetches stay in flight.
__global__ void __launch_bounds__(512, 1) nms_kernel(const float4* __restrict__ sbox,
                                                     const float* __restrict__ sscore,
                                                     const u64* __restrict__ mask,
                                                     float* __restrict__ out) {
  __shared__ u64 keepw[CBLK + 2];                // +2: b1==VB==132 tail write
  __shared__ u64 rem[CBLK + 2];
  int tid = threadIdx.x;
  int wave = tid >> 6, lane = tid & 63;

  // ---- n_valid via 2-round probe (redundant in every wave — same result)
  float s0 = sscore[lane * 132];                 // 63*132 = 8316 < 8400
  u64 pb = __ballot(s0 >= SCORE_THR);
  int cnt1 = (int)__popcll(pb);
  int n_valid = 0;
  if (cnt1 > 0) {
    int a = (cnt1 - 1) * 132 + 1;                // rows < a known valid
    int i1 = a + 3 * lane;
    float t1 = (i1 + 0 < N_ANCH) ? sscore[i1 + 0] : -1.f;
    float t2 = (i1 + 1 < N_ANCH) ? sscore[i1 + 1] : -1.f;
    float t3 = (i1 + 2 < N_ANCH) ? sscore[i1 + 2] : -1.f;
    u64 q1 = __ballot(t1 >= SCORE_THR);
    u64 q2 = __ballot(t2 >= SCORE_THR);
    u64 q3 = __ballot(t3 >= SCORE_THR);
    n_valid = a + (int)__popcll(q1) + (int)__popcll(q2) + (int)__popcll(q3);
  }
  int VB = (n_valid + 63) >> 6;                  // number of valid 64-blocks
  int NT = (VB + 1) >> 1;                        // 128-row iterations

  for (int b = tid; b < CBLK + 2; b += 512) { keepw[b] = 0; rem[b] = 0; }

  // ---- consume-wave state (waves 1..7): rows split 19x6 + 14
  int rs = (wave - 1) * 19;                      // row start within 128-pair
  int nr = 128 - rs; if (nr > 19) nr = 19;       // rows this wave owns
  u64 tl[19], th[19];                            // tile: cols cL / cL+64
  auto issue_tiles = [&](int u) {                // words 2u,2u+1 -> iter u+1
    int cL = 2 * u + 4 + lane;
    int cH = cL + 64;
    bool okL = (cL < VB), okH = (cH < VB);
    // rows 128u+rs..+18: u <= NT-2 <= 64 -> row <= 8324 < 8400, in-bounds
    const u64* pr = mask + (u64)(128 * u + rs) * CBLK;
    #pragma unroll
    for (int r = 0; r < 19; ++r) {
      bool rok = (r < nr);
      tl[r] = (rok && okL) ? pr[(u64)r * CBLK + cL] : 0ull;
      th[r] = (rok && okH) ? pr[(u64)r * CBLK + cH] : 0ull;
    }
  };

  // ---- wave-0 state: COLUMN words (wLo region), double-buffered. Lane i:
  //   cA = col word of box 64b0+i vs rows b0   (diag block)
  //   cB = col word of box 64b1+i vs rows b0   (below-diag)
  //   cC = col word of box 64b1+i vs rows b1   (diag)
  //   cD0/cD1 = col word of box 64(b0+2)+i vs rows b0 / b1
  //   cE0/cE1 = col word of box 64(b0+3)+i vs rows b0 / b1
  u64 cA=0,cB=0,cC=0,cD0=0,cD1=0,cE0=0,cE1=0;
  u64 nA=0,nB=0,nC=0,nD0=0,nD1=0,nE0=0,nE1=0;
  auto load_w0 = [&](int T2, u64&A,u64&B,u64&C,u64&D0,u64&D1,u64&E0,u64&E1) {
    int b0 = 2 * T2, b1 = b0 + 1;
    int r0 = b0 * 64 + lane;                     // b0<=130 -> <=8383, safe
    int r1 = b1 * 64 + lane; if (r1 > N_ANCH - 1) r1 = N_ANCH - 1;
    int r2 = (b0 + 2) * 64 + lane; if (r2 > N_ANCH - 1) r2 = N_ANCH - 1;
    int r3 = (b0 + 3) * 64 + lane; if (r3 > N_ANCH - 1) r3 = N_ANCH - 1;
    // clamped lanes = boxes >= n_valid; their spurious bits are masked by
    // vm (act) or land on invalid lanes — never affect a valid keep bit.
    bool ok1 = (b1 < VB), ok2 = (b0 + 2 < VB), ok3 = (b0 + 3 < VB);
    const u64* p0 = mask + (u64)r0 * CBLK;
    const u64* p1 = mask + (u64)r1 * CBLK;
    const u64* p2 = mask + (u64)r2 * CBLK;
    const u64* p3 = mask + (u64)r3 * CBLK;
    A  = p0[b0];
    B  = ok1 ? p1[b0] : 0ull;
    C  = ok1 ? p1[b1] : 0ull;
    D0 = ok2 ? p2[b0] : 0ull;
    D1 = ok2 ? p2[b1] : 0ull;
    E0 = ok3 ? p3[b0] : 0ull;
    E1 = ok3 ? p3[b1] : 0ull;
  };

  u64 carry0 = 0, carry1 = 0;                    // words b0-2,b0-1 -> cols b0,b1

  if (wave == 0 && NT > 0) load_w0(0, cA,cB,cC,cD0,cD1,cE0,cE1);

  for (int T = 0; T < NT; ++T) {
    // one barrier per iteration; LDS-only drain — global loads stay in flight
    asm volatile("s_waitcnt lgkmcnt(0)\ns_barrier" ::: "memory");

    if (wave == 0) {
      int b0 = 2 * T, b1 = b0 + 1;
      u64 rb0 = rem[b0], rb1 = rem[b1];          // issue ds_reads early
      // rotate double buffer; issue next iteration's 7 loads immediately
      if (T > 0) { cA=nA; cB=nB; cC=nC; cD0=nD0; cD1=nD1; cE0=nE0; cE1=nE1; }
      if (T + 1 < NT) load_w0(T + 1, nA,nB,nC,nD0,nD1,nE0,nE1);

      u64 remb0 = rfl64(rb0 | carry0);
      u64 remb1 = rfl64(rb1 | carry1);
      int remn0 = n_valid - b0 * 64;             // >= 1
      int remn1 = remn0 - 64;
      u64 vm0 = (remn0 >= 64) ? ~0ull : ((1ull << remn0) - 1ull);
      u64 vm1 = (remn1 >= 64) ? ~0ull
              : ((remn1 <= 0) ? 0ull : ((1ull << remn1) - 1ull));
      u64 act0 = vm0 & ~remb0;                   // SGPR
      u64 act1 = vm1 & ~remb1;                   // SGPR

      // ---- word0: ballot-round greedy fixpoint
      u64 U = act0, K0 = 0;
      while (U) {
        u64 covered = __ballot((cA & U) != 0ull);
        u64 nk = U & ~covered;                   // definite keepers
        u64 supp = __ballot((cA & nk) != 0ull);  // definitely suppressed
        K0 |= nk;
        U &= ~(nk | supp);
      }
      u64 kw0 = K0;

      // ---- word1: remove word0-keeper suppression (one ballot), then scan
      u64 s01 = __ballot((cB & kw0) != 0ull);
      u64 U1 = act1 & ~s01, K1 = 0;
      while (U1) {
        u64 covered = __ballot((cC & U1) != 0ull);
        u64 nk = U1 & ~covered;
        u64 supp = __ballot((cC & nk) != 0ull);
        K1 |= nk;
        U1 &= ~(nk | supp);
      }
      u64 kw1 = K1;

      if (lane == 0) { keepw[b0] = kw0; keepw[b1] = kw1; }

      // ---- carry: contribution of words b0,b1 to cols b0+2,b0+3 (2 ballots)
      carry0 = __ballot(((cD0 & kw0) | (cD1 & kw1)) != 0ull);
      carry1 = __ballot(((cE0 & kw0) | (cE1 & kw1)) != 0ull);
    } else {
      // ---- consume iteration T-1's keeps, concurrent with wave0's scan
      if (T > 0) {
        int u = T - 1;
        u64 kws0 = rfl64(keepw[2 * u]);          // broadcast read
        u64 kws1 = rfl64(keepw[2 * u + 1]);
        u64 accL = 0, accH = 0;
        #pragma unroll
        for (int r = 0; r < 19; ++r) {
          int rr = rs + r;                       // wave-uniform
          u64 bit = (rr < 64) ? (kws0 >> rr) : (kws1 >> (rr - 64));
          u64 sm = (u64)0 - (bit & 1ull);
          accL |= tl[r] & sm;
          accH |= th[r] & sm;
        }
        int cL = 2 * u + 4 + lane, cH = cL + 64;
        if (cL < VB && accL) atomicOr((unsigned long long*)&rem[cL], accL);
        if (cH < VB && accH) atomicOr((unsigned long long*)&rem[cH], accH);
      }
      // refill tiles for iteration T+1 (regs just consumed)
      if (T + 1 < NT) issue_tiles(T);
    }
  }
  __syncthreads();

  // ---- fused masked output (512 threads)
  for (int r2 = tid; r2 < N_ANCH; r2 += 512) {
    u64 kv = keepw[r2 >> 6];
    bool kp = (kv >> (r2 & 63)) & 1ull;
    float4 b4 = sbox[r2];
    float sc = sscore[r2];
    float* o = out + r2 * 5;
    o[0] = kp ? b4.x : 0.f;
    o[1] = kp ? b4.y : 0.f;
    o[2] = kp ? b4.z : 0.f;
    o[3] = kp ? b4.w : 0.f;
    o[4] = kp ? sc : 0.f;
  }
}

extern "C" void kernel_launch(void* const* d_in, const int* in_sizes, int n_in,
                              void* d_out, int out_size, void* d_ws, size_t ws_size,
                              hipStream_t stream) {
  const float* raw = (const float*)d_in[0];
  float* out = (float*)d_out;
  char* ws = (char*)d_ws;
  // ws layout: sbox (8448*16 B) | sscore (8448*4 B) | mask (8400*132*8 B) ≈ 9.04 MB
  float4* sbox = (float4*)ws;
  float* sscore = (float*)(ws + 8448 * 16);
  u64* mask = (u64*)(ws + 8448 * 16 + 8448 * 4);

  rank_kernel<<<2100, 256, 0, stream>>>(raw, sbox, sscore);
  mask_kernel<<<dim3(CBLK, 33), 256, 0, stream>>>(sbox, sscore, mask);
  nms_kernel<<<1, 512, 0, stream>>>(sbox, sscore, mask, out);
}

// Round 5
// 155.100 us; speedup vs baseline: 1.1228x; 1.1228x over previous
//
#include <hip/hip_runtime.h>
#include <cstdint>

#define N_ANCH 8400
#define CBLK 132              // ceil(8400/64)
#define SCORE_THR 0.5f

typedef unsigned long long u64;
typedef unsigned int u32;

// Sort key: ascending sort == (valid score descending, then index ascending,
// invalid last by index ascending) — exactly matches
// argsort(-where(valid, s, -inf)) with stable ties.
__device__ __forceinline__ u64 sort_key(float s, int idx) {
  u32 k32 = (s >= SCORE_THR) ? ~__float_as_uint(s) : 0xFFFFFFFFu;
  return ((u64)k32 << 32) | (u32)idx;
}

// Force a wave-uniform u64 into SGPRs.
__device__ __forceinline__ u64 rfl64(u64 v) {
  u32 lo = (u32)__builtin_amdgcn_readfirstlane((int)(u32)v);
  u32 hi = (u32)__builtin_amdgcn_readfirstlane((int)(u32)(v >> 32));
  return ((u64)hi << 32) | lo;
}

// One 64-lane wave per anchor: rank = #{keys smaller}, then scatter
// decoded box + score into sorted position.
__global__ void __launch_bounds__(256) rank_kernel(const float* __restrict__ raw,
                                                   float4* __restrict__ sbox,
                                                   float* __restrict__ sscore) {
  #pragma clang fp contract(off)
  int tid = blockIdx.x * 256 + threadIdx.x;
  int row = tid >> 6, lane = tid & 63;
  if (row >= N_ANCH) return;
  float si = raw[4 * N_ANCH + row];
  u64 ki = sort_key(si, row);
  int cnt = 0;
  for (int j = lane; j < N_ANCH; j += 64) {
    float sj = raw[4 * N_ANCH + j];
    cnt += (sort_key(sj, j) < ki) ? 1 : 0;
  }
  #pragma unroll
  for (int d = 1; d < 64; d <<= 1) cnt += __shfl_xor(cnt, d, 64);
  if (lane == 0) {
    float cx = raw[row], cy = raw[N_ANCH + row];
    float w = raw[2 * N_ANCH + row], h = raw[3 * N_ANCH + row];
    float hw = w * 0.5f, hh = h * 0.5f;
    sbox[cnt] = make_float4(cx - hw, cy - hh, cx + hw, cy + hh);
    sscore[cnt] = si;
  }
}

// Suppression bitmask over sorted boxes, dual-format, one array:
//   cb > (i>>6): wHi — bit jj set iff jg>i and iou>0.5 (row word). Read by
//                nms consume tiles (only at col-distance >= 3).
//   cb <= (i>>6): wLo — bit jj set iff jg<i and iou>0.5 (COLUMN word). Read
//                by nms wave0's ballot scan/carry — ONLY at distance <= 3.
// Band skip: cells with cb < rowblk-3 are never read by nms (tiles start at
// distance 3-4 above diag; wLo reads are distance 0..3 below). A 256-row
// y-block spans rowblocks ry..ry+3, so skip iff cb+3 < ry. Skipped blocks
// leave stale workspace — provably unread (tiles check col<VB & rows above;
// wave0 reads only computed near-diag blocks).
__global__ void __launch_bounds__(256) mask_kernel(const float4* __restrict__ sbox,
                                                   const float* __restrict__ sscore,
                                                   u64* __restrict__ mask) {
  #pragma clang fp contract(off)
  int cb = blockIdx.x;
  int i0 = blockIdx.y * 256;
  if (cb + 3 < (i0 >> 6)) return;                // below-diagonal band skip
  if (!(sscore[i0] >= SCORE_THR)) return;        // whole row-block invalid
  if (!(sscore[cb * 64] >= SCORE_THR)) return;   // whole col-block invalid
  int t = threadIdx.x;
  __shared__ float4 cbox[64];
  __shared__ float carea[64];
  int j0 = cb * 64;
  if (t < 64) {
    int j = j0 + t;
    float4 bj = (j < N_ANCH) ? sbox[j] : make_float4(0.f, 0.f, 0.f, 0.f);
    cbox[t] = bj;
    carea[t] = (bj.z - bj.x) * (bj.w - bj.y);
  }
  __syncthreads();
  int i = i0 + t;
  if (i >= N_ANCH) return;
  float4 bi = sbox[i];
  float ai = (bi.z - bi.x) * (bi.w - bi.y);
  u64 wHi = 0, wLo = 0;
  for (int jj = 0; jj < 64; ++jj) {
    int jg = j0 + jj;
    float4 bb = cbox[jj];
    float ltx = fmaxf(bi.x, bb.x), lty = fmaxf(bi.y, bb.y);
    float rbx = fminf(bi.z, bb.z), rby = fminf(bi.w, bb.w);
    float wx = fmaxf(rbx - ltx, 0.f), wy = fmaxf(rby - lty, 0.f);
    float inter = wx * wy;
    float uni = (ai + carea[jj]) - inter;      // same op order as reference
    float iou = inter / fmaxf(uni, 1e-9f);     // IEEE div, matches numpy
    bool sup = (iou > 0.5f) && (jg < N_ANCH);
    wHi |= (u64)(sup && (jg > i)) << jj;
    wLo |= (u64)(sup && (jg < i)) << jj;
  }
  mask[(u64)i * CBLK + cb] = (cb > (i >> 6)) ? wHi : wLo;
}

// PIPELINED NMS, ballot scan (wave 0) overlapped with consume (waves 1-7),
// one barrier per iteration. This round: runtime-dead-work elimination in
// the consume path. At the actual data's VB~66, the H column-set
// (cH = 2u+68+lane) is out of range for EVERY iteration — its 19 loads'
// address calc and 76 VALU of masked-OR per wave per iter were pure waste
// the compiler can't remove (VB is runtime). Wave-uniform guards skip the
// H half (and the L half in the tail iterations) entirely. Wave 0 runs its
// scan at s_setprio(1) (role-split wave; shares a SIMD with a consume wave).
__global__ void __launch_bounds__(512, 1) nms_kernel(const float4* __restrict__ sbox,
                                                     const float* __restrict__ sscore,
                                                     const u64* __restrict__ mask,
                                                     float* __restrict__ out) {
  __shared__ u64 keepw[CBLK + 2];                // +2: b1==VB==132 tail write
  __shared__ u64 rem[CBLK + 2];
  int tid = threadIdx.x;
  int wave = tid >> 6, lane = tid & 63;

  // ---- n_valid via 2-round probe (redundant in every wave — same result)
  float s0 = sscore[lane * 132];                 // 63*132 = 8316 < 8400
  u64 pb = __ballot(s0 >= SCORE_THR);
  int cnt1 = (int)__popcll(pb);
  int n_valid = 0;
  if (cnt1 > 0) {
    int a = (cnt1 - 1) * 132 + 1;                // rows < a known valid
    int i1 = a + 3 * lane;
    float t1 = (i1 + 0 < N_ANCH) ? sscore[i1 + 0] : -1.f;
    float t2 = (i1 + 1 < N_ANCH) ? sscore[i1 + 1] : -1.f;
    float t3 = (i1 + 2 < N_ANCH) ? sscore[i1 + 2] : -1.f;
    u64 q1 = __ballot(t1 >= SCORE_THR);
    u64 q2 = __ballot(t2 >= SCORE_THR);
    u64 q3 = __ballot(t3 >= SCORE_THR);
    n_valid = a + (int)__popcll(q1) + (int)__popcll(q2) + (int)__popcll(q3);
  }
  int VB = (n_valid + 63) >> 6;                  // number of valid 64-blocks
  int NT = (VB + 1) >> 1;                        // 128-row iterations

  for (int b = tid; b < CBLK + 2; b += 512) { keepw[b] = 0; rem[b] = 0; }

  // ---- consume-wave state (waves 1..7): rows split 19x6 + 14
  int rs = (wave - 1) * 19;                      // row start within 128-pair
  int nr = 128 - rs; if (nr > 19) nr = 19;       // rows this wave owns
  u64 tl[19], th[19];                            // tile: cols cL / cL+64
  auto issue_tiles = [&](int u) {                // words 2u,2u+1 -> iter u+1
    int base = 2 * u + 4;
    if (base >= VB) return;                      // tail: nothing left
    int cL = base + lane;
    bool okL = (cL < VB);
    // rows 128u+rs..+18: u <= NT-2 <= 64 -> row <= 8319 < 8400, in-bounds
    const u64* pr = mask + (u64)(128 * u + rs) * CBLK;
    #pragma unroll
    for (int r = 0; r < 19; ++r) {
      bool rok = (r < nr);
      tl[r] = (rok && okL) ? pr[(u64)r * CBLK + cL] : 0ull;
    }
    if (base + 64 < VB) {                        // H half exists at all?
      int cH = cL + 64;
      bool okH = (cH < VB);
      #pragma unroll
      for (int r = 0; r < 19; ++r) {
        bool rok = (r < nr);
        th[r] = (rok && okH) ? pr[(u64)r * CBLK + cH] : 0ull;
      }
    }
  };

  // ---- wave-0 state: COLUMN words (wLo region), double-buffered. Lane i:
  //   cA = col word of box 64b0+i vs rows b0   (diag block)
  //   cB = col word of box 64b1+i vs rows b0   (below-diag)
  //   cC = col word of box 64b1+i vs rows b1   (diag)
  //   cD0/cD1 = col word of box 64(b0+2)+i vs rows b0 / b1
  //   cE0/cE1 = col word of box 64(b0+3)+i vs rows b0 / b1
  u64 cA=0,cB=0,cC=0,cD0=0,cD1=0,cE0=0,cE1=0;
  u64 nA=0,nB=0,nC=0,nD0=0,nD1=0,nE0=0,nE1=0;
  auto load_w0 = [&](int T2, u64&A,u64&B,u64&C,u64&D0,u64&D1,u64&E0,u64&E1) {
    int b0 = 2 * T2, b1 = b0 + 1;
    int r0 = b0 * 64 + lane;                     // b0<=130 -> <=8383, safe
    int r1 = b1 * 64 + lane; if (r1 > N_ANCH - 1) r1 = N_ANCH - 1;
    int r2 = (b0 + 2) * 64 + lane; if (r2 > N_ANCH - 1) r2 = N_ANCH - 1;
    int r3 = (b0 + 3) * 64 + lane; if (r3 > N_ANCH - 1) r3 = N_ANCH - 1;
    // clamped lanes = boxes >= n_valid; spurious bits are masked by vm (act)
    // or land on invalid lanes — never affect a valid keep bit.
    bool ok1 = (b1 < VB), ok2 = (b0 + 2 < VB), ok3 = (b0 + 3 < VB);
    const u64* p0 = mask + (u64)r0 * CBLK;
    const u64* p1 = mask + (u64)r1 * CBLK;
    const u64* p2 = mask + (u64)r2 * CBLK;
    const u64* p3 = mask + (u64)r3 * CBLK;
    A  = p0[b0];
    B  = ok1 ? p1[b0] : 0ull;
    C  = ok1 ? p1[b1] : 0ull;
    D0 = ok2 ? p2[b0] : 0ull;
    D1 = ok2 ? p2[b1] : 0ull;
    E0 = ok3 ? p3[b0] : 0ull;
    E1 = ok3 ? p3[b1] : 0ull;
  };

  u64 carry0 = 0, carry1 = 0;                    // words b0-2,b0-1 -> cols b0,b1

  if (wave == 0 && NT > 0) load_w0(0, cA,cB,cC,cD0,cD1,cE0,cE1);

  for (int T = 0; T < NT; ++T) {
    // one barrier per iteration; LDS-only drain — global loads stay in flight
    asm volatile("s_waitcnt lgkmcnt(0)\ns_barrier" ::: "memory");

    if (wave == 0) {
      __builtin_amdgcn_s_setprio(1);             // favor the serial scan wave
      int b0 = 2 * T, b1 = b0 + 1;
      u64 rb0 = rem[b0], rb1 = rem[b1];          // issue ds_reads early
      // rotate double buffer; issue next iteration's 7 loads immediately
      if (T > 0) { cA=nA; cB=nB; cC=nC; cD0=nD0; cD1=nD1; cE0=nE0; cE1=nE1; }
      if (T + 1 < NT) load_w0(T + 1, nA,nB,nC,nD0,nD1,nE0,nE1);

      u64 remb0 = rfl64(rb0 | carry0);
      u64 remb1 = rfl64(rb1 | carry1);
      int remn0 = n_valid - b0 * 64;             // >= 1
      int remn1 = remn0 - 64;
      u64 vm0 = (remn0 >= 64) ? ~0ull : ((1ull << remn0) - 1ull);
      u64 vm1 = (remn1 >= 64) ? ~0ull
              : ((remn1 <= 0) ? 0ull : ((1ull << remn1) - 1ull));
      u64 act0 = vm0 & ~remb0;                   // SGPR
      u64 act1 = vm1 & ~remb1;                   // SGPR

      // ---- word0: ballot-round greedy fixpoint
      u64 U = act0, K0 = 0;
      while (U) {
        u64 covered = __ballot((cA & U) != 0ull);
        u64 nk = U & ~covered;                   // definite keepers
        u64 supp = __ballot((cA & nk) != 0ull);  // definitely suppressed
        K0 |= nk;
        U &= ~(nk | supp);
      }
      u64 kw0 = K0;

      // ---- word1: remove word0-keeper suppression (one ballot), then scan
      u64 s01 = __ballot((cB & kw0) != 0ull);
      u64 U1 = act1 & ~s01, K1 = 0;
      while (U1) {
        u64 covered = __ballot((cC & U1) != 0ull);
        u64 nk = U1 & ~covered;
        u64 supp = __ballot((cC & nk) != 0ull);
        K1 |= nk;
        U1 &= ~(nk | supp);
      }
      u64 kw1 = K1;

      if (lane == 0) { keepw[b0] = kw0; keepw[b1] = kw1; }

      // ---- carry: contribution of words b0,b1 to cols b0+2,b0+3 (2 ballots)
      carry0 = __ballot(((cD0 & kw0) | (cD1 & kw1)) != 0ull);
      carry1 = __ballot(((cE0 & kw0) | (cE1 & kw1)) != 0ull);
      __builtin_amdgcn_s_setprio(0);             // yield while others consume
    } else {
      // ---- consume iteration T-1's keeps, concurrent with wave0's scan.
      // Wave-uniform guards skip runtime-dead halves (VB~66 => H never runs).
      if (T > 0) {
        int u = T - 1;
        int base = 2 * u + 4;
        if (base < VB) {
          u64 kws0 = rfl64(keepw[2 * u]);        // broadcast read
          u64 kws1 = rfl64(keepw[2 * u + 1]);
          u64 accL = 0;
          #pragma unroll
          for (int r = 0; r < 19; ++r) {
            int rr = rs + r;                     // wave-uniform
            u64 bit = (rr < 64) ? (kws0 >> rr) : (kws1 >> (rr - 64));
            u64 sm = (u64)0 - (bit & 1ull);
            accL |= tl[r] & sm;
          }
          int cL = base + lane;
          if (cL < VB && accL) atomicOr((unsigned long long*)&rem[cL], accL);
          if (base + 64 < VB) {                  // H half exists at all?
            u64 accH = 0;
            #pragma unroll
            for (int r = 0; r < 19; ++r) {
              int rr = rs + r;
              u64 bit = (rr < 64) ? (kws0 >> rr) : (kws1 >> (rr - 64));
              u64 sm = (u64)0 - (bit & 1ull);
              accH |= th[r] & sm;
            }
            int cH = base + 64 + lane;
            if (cH < VB && accH) atomicOr((unsigned long long*)&rem[cH], accH);
          }
        }
      }
      // refill tiles for iteration T+1 (regs just consumed)
      if (T + 1 < NT) issue_tiles(T);
    }
  }
  __syncthreads();

  // ---- fused masked output (512 threads)
  for (int r2 = tid; r2 < N_ANCH; r2 += 512) {
    u64 kv = keepw[r2 >> 6];
    bool kp = (kv >> (r2 & 63)) & 1ull;
    float4 b4 = sbox[r2];
    float sc = sscore[r2];
    float* o = out + r2 * 5;
    o[0] = kp ? b4.x : 0.f;
    o[1] = kp ? b4.y : 0.f;
    o[2] = kp ? b4.z : 0.f;
    o[3] = kp ? b4.w : 0.f;
    o[4] = kp ? sc : 0.f;
  }
}

extern "C" void kernel_launch(void* const* d_in, const int* in_sizes, int n_in,
                              void* d_out, int out_size, void* d_ws, size_t ws_size,
                              hipStream_t stream) {
  const float* raw = (const float*)d_in[0];
  float* out = (float*)d_out;
  char* ws = (char*)d_ws;
  // ws layout: sbox (8448*16 B) | sscore (8448*4 B) | mask (8400*132*8 B) ≈ 9.04 MB
  float4* sbox = (float4*)ws;
  float* sscore = (float*)(ws + 8448 * 16);
  u64* mask = (u64*)(ws + 8448 * 16 + 8448 * 4);

  rank_kernel<<<2100, 256, 0, stream>>>(raw, sbox, sscore);
  mask_kernel<<<dim3(CBLK, 33), 256, 0, stream>>>(sbox, sscore, mask);
  nms_kernel<<<1, 512, 0, stream>>>(sbox, sscore, mask, out);
}

// Round 6
// 147.447 us; speedup vs baseline: 1.1811x; 1.0519x over previous
//
#include <hip/hip_runtime.h>
#include <cstdint>

#define N_ANCH 8400
#define CBLK 132              // ceil(8400/64)
#define SCORE_THR 0.5f

typedef unsigned long long u64;
typedef unsigned int u32;

// Sort key: ascending sort == (valid score descending, then index ascending,
// invalid last by index ascending) — exactly matches
// argsort(-where(valid, s, -inf)) with stable ties.
__device__ __forceinline__ u64 sort_key(float s, int idx) {
  u32 k32 = (s >= SCORE_THR) ? ~__float_as_uint(s) : 0xFFFFFFFFu;
  return ((u64)k32 << 32) | (u32)idx;
}

// Force a wave-uniform u64 into SGPRs.
__device__ __forceinline__ u64 rfl64(u64 v) {
  u32 lo = (u32)__builtin_amdgcn_readfirstlane((int)(u32)v);
  u32 hi = (u32)__builtin_amdgcn_readfirstlane((int)(u32)(v >> 32));
  return ((u64)hi << 32) | lo;
}

// One 64-lane wave per anchor: rank = #{keys smaller}, then scatter
// decoded box + score into sorted position.
__global__ void __launch_bounds__(256) rank_kernel(const float* __restrict__ raw,
                                                   float4* __restrict__ sbox,
                                                   float* __restrict__ sscore) {
  #pragma clang fp contract(off)
  int tid = blockIdx.x * 256 + threadIdx.x;
  int row = tid >> 6, lane = tid & 63;
  if (row >= N_ANCH) return;
  float si = raw[4 * N_ANCH + row];
  u64 ki = sort_key(si, row);
  int cnt = 0;
  for (int j = lane; j < N_ANCH; j += 64) {
    float sj = raw[4 * N_ANCH + j];
    cnt += (sort_key(sj, j) < ki) ? 1 : 0;
  }
  #pragma unroll
  for (int d = 1; d < 64; d <<= 1) cnt += __shfl_xor(cnt, d, 64);
  if (lane == 0) {
    float cx = raw[row], cy = raw[N_ANCH + row];
    float w = raw[2 * N_ANCH + row], h = raw[3 * N_ANCH + row];
    float hw = w * 0.5f, hh = h * 0.5f;
    sbox[cnt] = make_float4(cx - hw, cy - hh, cx + hw, cy + hh);
    sscore[cnt] = si;
  }
}

// Suppression bitmask over sorted boxes, dual-format, one array:
//   cb > (i>>6): wHi — bit jj set iff jg>i and iou>0.5 (row word). Read by
//                nms consume tiles (only at col-distance >= 5).
//   cb <= (i>>6): wLo — bit jj set iff jg<i and iou>0.5 (COLUMN word). Read
//                by nms wave0's scan/carry — at diagonal distance <= 5 now
//                (carry widened to 4 columns).
// Band skip: a 256-row y-block spans rowblocks ry..ry+3; wLo cells are read
// only at distance <= 5, so skip iff cb + 5 < ry. Skipped cells leave stale
// workspace — provably unread.
__global__ void __launch_bounds__(256) mask_kernel(const float4* __restrict__ sbox,
                                                   const float* __restrict__ sscore,
                                                   u64* __restrict__ mask) {
  #pragma clang fp contract(off)
  int cb = blockIdx.x;
  int i0 = blockIdx.y * 256;
  if (cb + 5 < (i0 >> 6)) return;                // below-diagonal band skip
  if (!(sscore[i0] >= SCORE_THR)) return;        // whole row-block invalid
  if (!(sscore[cb * 64] >= SCORE_THR)) return;   // whole col-block invalid
  int t = threadIdx.x;
  __shared__ float4 cbox[64];
  __shared__ float carea[64];
  int j0 = cb * 64;
  if (t < 64) {
    int j = j0 + t;
    float4 bj = (j < N_ANCH) ? sbox[j] : make_float4(0.f, 0.f, 0.f, 0.f);
    cbox[t] = bj;
    carea[t] = (bj.z - bj.x) * (bj.w - bj.y);
  }
  __syncthreads();
  int i = i0 + t;
  if (i >= N_ANCH) return;
  float4 bi = sbox[i];
  float ai = (bi.z - bi.x) * (bi.w - bi.y);
  u64 wHi = 0, wLo = 0;
  for (int jj = 0; jj < 64; ++jj) {
    int jg = j0 + jj;
    float4 bb = cbox[jj];
    float ltx = fmaxf(bi.x, bb.x), lty = fmaxf(bi.y, bb.y);
    float rbx = fminf(bi.z, bb.z), rby = fminf(bi.w, bb.w);
    float wx = fmaxf(rbx - ltx, 0.f), wy = fmaxf(rby - lty, 0.f);
    float inter = wx * wy;
    float uni = (ai + carea[jj]) - inter;      // same op order as reference
    float iou = inter / fmaxf(uni, 1e-9f);     // IEEE div, matches numpy
    bool sup = (iou > 0.5f) && (jg < N_ANCH);
    wHi |= (u64)(sup && (jg > i)) << jj;
    wLo |= (u64)(sup && (jg < i)) << jj;
  }
  mask[(u64)i * CBLK + cb] = (cb > (i >> 6)) ? wHi : wLo;
}

// PIPELINED NMS with KEEPER-FILTERED lag-2 consume.
// Wave 0 scans words 2T,2T+1 at iter T (ballot fixpoint). Consume waves
// (1-7) now issue tile loads ONLY for keeper rows: at iter T, keepw[2(T-1)]
// is already published (iter T-1), so loads for word-pair 2(T-1) are gated
// per-row by the keep bit (suppressed rows load as 0 — masking moved to
// load time, the OR loop is mask-free). Consumption happens at iter T+1
// (full iteration of load slack). This cuts tile VMEM traffic AND consume
// VALU by the keep rate (~3-5x).
//
// Pipeline coverage (word W=2u affects col c>W): c=W in-scan (cA); c=W+1
// coupling ballot (cB); c=W+2..W+5 wave0 register carries — f2..f5 ballots
// over prefetched column words D/E/F/G, landing at iter u+1 (lag-1 pair
// p0/p1) and u+2 (lag-2 pair q0/q1); c>=W+6 consume tiles, L-half
// [W+6,W+70) + H-half [W+70,W+134) — covers VB<=132. Consume at iter X
// writes cols >= 2X+2, never racing wave0's rem[2X,2X+1] reads; keepw
// writes (words 2T,2T+1) never race consume's keepw[2T-2,2T-1] reads.
// Barriers drain LDS ONLY (lgkmcnt) — global prefetches stay in flight.
__global__ void __launch_bounds__(512, 1) nms_kernel(const float4* __restrict__ sbox,
                                                     const float* __restrict__ sscore,
                                                     const u64* __restrict__ mask,
                                                     float* __restrict__ out) {
  __shared__ u64 keepw[CBLK + 2];                // +2: b1==VB==132 tail write
  __shared__ u64 rem[CBLK + 2];
  int tid = threadIdx.x;
  int wave = tid >> 6, lane = tid & 63;

  // ---- n_valid via 2-round probe (redundant in every wave — same result)
  float s0 = sscore[lane * 132];                 // 63*132 = 8316 < 8400
  u64 pb = __ballot(s0 >= SCORE_THR);
  int cnt1 = (int)__popcll(pb);
  int n_valid = 0;
  if (cnt1 > 0) {
    int a = (cnt1 - 1) * 132 + 1;                // rows < a known valid
    int i1 = a + 3 * lane;
    float t1 = (i1 + 0 < N_ANCH) ? sscore[i1 + 0] : -1.f;
    float t2 = (i1 + 1 < N_ANCH) ? sscore[i1 + 1] : -1.f;
    float t3 = (i1 + 2 < N_ANCH) ? sscore[i1 + 2] : -1.f;
    u64 q1 = __ballot(t1 >= SCORE_THR);
    u64 q2 = __ballot(t2 >= SCORE_THR);
    u64 q3 = __ballot(t3 >= SCORE_THR);
    n_valid = a + (int)__popcll(q1) + (int)__popcll(q2) + (int)__popcll(q3);
  }
  int VB = (n_valid + 63) >> 6;                  // number of valid 64-blocks
  int NT = (VB + 1) >> 1;                        // 128-row iterations

  for (int b = tid; b < CBLK + 2; b += 512) { keepw[b] = 0; rem[b] = 0; }

  // ---- consume-wave state (waves 1..7): rows split 19x6 + 14
  int rs = (wave - 1) * 19;                      // row start within 128-pair
  int nr = 128 - rs; if (nr > 19) nr = 19;       // rows this wave owns
  u64 tl[19], th[19];                            // keeper-filtered tiles

  // ---- wave-0 state: COLUMN words (wLo region), double-buffered. Lane i:
  //   cA  = col word of box 64b0+i    vs rows b0  (diag, d=0)
  //   cB  = col word of box 64b1+i    vs rows b0  (d=1)
  //   cC  = col word of box 64b1+i    vs rows b1  (diag, d=0)
  //   cD0/cD1 = col word of box 64(b0+2)+i vs rows b0/b1  (d=2/1)
  //   cE0/cE1 = col word of box 64(b0+3)+i vs rows b0/b1  (d=3/2)
  //   cF0/cF1 = col word of box 64(b0+4)+i vs rows b0/b1  (d=4/3)
  //   cG0/cG1 = col word of box 64(b0+5)+i vs rows b0/b1  (d=5/4)
  u64 cA=0,cB=0,cC=0,cD0=0,cD1=0,cE0=0,cE1=0,cF0=0,cF1=0,cG0=0,cG1=0;
  u64 nA=0,nB=0,nC=0,nD0=0,nD1=0,nE0=0,nE1=0,nF0=0,nF1=0,nG0=0,nG1=0;
  auto load_w0 = [&](int T2, u64&A,u64&B,u64&C,u64&D0,u64&D1,u64&E0,u64&E1,
                     u64&F0,u64&F1,u64&G0,u64&G1) {
    int b0 = 2 * T2, b1 = b0 + 1;
    int r0 = b0 * 64 + lane;                     // b0<=130 -> <=8383, safe
    int r1 = b1 * 64 + lane; if (r1 > N_ANCH - 1) r1 = N_ANCH - 1;
    int r2 = (b0 + 2) * 64 + lane; if (r2 > N_ANCH - 1) r2 = N_ANCH - 1;
    int r3 = (b0 + 3) * 64 + lane; if (r3 > N_ANCH - 1) r3 = N_ANCH - 1;
    int r4 = (b0 + 4) * 64 + lane; if (r4 > N_ANCH - 1) r4 = N_ANCH - 1;
    int r5 = (b0 + 5) * 64 + lane; if (r5 > N_ANCH - 1) r5 = N_ANCH - 1;
    // clamped lanes = boxes >= n_valid; spurious bits are masked by vm (act)
    // or land on invalid lanes — never affect a valid keep bit.
    bool ok1 = (b1 < VB), ok2 = (b0 + 2 < VB), ok3 = (b0 + 3 < VB);
    bool ok4 = (b0 + 4 < VB), ok5 = (b0 + 5 < VB);
    const u64* p0 = mask + (u64)r0 * CBLK;
    const u64* p1 = mask + (u64)r1 * CBLK;
    const u64* p2 = mask + (u64)r2 * CBLK;
    const u64* p3 = mask + (u64)r3 * CBLK;
    const u64* p4 = mask + (u64)r4 * CBLK;
    const u64* p5 = mask + (u64)r5 * CBLK;
    A  = p0[b0];
    B  = ok1 ? p1[b0] : 0ull;
    C  = ok1 ? p1[b1] : 0ull;
    D0 = ok2 ? p2[b0] : 0ull;  D1 = ok2 ? p2[b1] : 0ull;
    E0 = ok3 ? p3[b0] : 0ull;  E1 = ok3 ? p3[b1] : 0ull;
    F0 = ok4 ? p4[b0] : 0ull;  F1 = ok4 ? p4[b1] : 0ull;
    G0 = ok5 ? p5[b0] : 0ull;  G1 = ok5 ? p5[b1] : 0ull;
  };

  u64 p0c = 0, p1c = 0;                          // lag-1 carry -> cols 2T,2T+1
  u64 q0c = 0, q1c = 0;                          // lag-2 carry -> cols 2T,2T+1
  u64 qn0 = 0, qn1 = 0;                          // staging for next lag-2

  if (wave == 0 && NT > 0)
    load_w0(0, cA,cB,cC,cD0,cD1,cE0,cE1,cF0,cF1,cG0,cG1);

  for (int T = 0; T < NT; ++T) {
    // one barrier per iteration; LDS-only drain — global loads stay in flight
    asm volatile("s_waitcnt lgkmcnt(0)\ns_barrier" ::: "memory");

    if (wave == 0) {
      __builtin_amdgcn_s_setprio(1);             // favor the serial scan wave
      int b0 = 2 * T, b1 = b0 + 1;
      u64 rb0 = rem[b0], rb1 = rem[b1];          // issue ds_reads early
      // rotate double buffer; issue next iteration's 11 loads immediately
      if (T > 0) { cA=nA; cB=nB; cC=nC; cD0=nD0; cD1=nD1; cE0=nE0; cE1=nE1;
                   cF0=nF0; cF1=nF1; cG0=nG0; cG1=nG1; }
      if (T + 1 < NT)
        load_w0(T + 1, nA,nB,nC,nD0,nD1,nE0,nE1,nF0,nF1,nG0,nG1);

      u64 remb0 = rfl64(rb0) | p0c | q0c;        // carries already SGPR
      u64 remb1 = rfl64(rb1) | p1c | q1c;
      int remn0 = n_valid - b0 * 64;             // >= 1
      int remn1 = remn0 - 64;
      u64 vm0 = (remn0 >= 64) ? ~0ull : ((1ull << remn0) - 1ull);
      u64 vm1 = (remn1 >= 64) ? ~0ull
              : ((remn1 <= 0) ? 0ull : ((1ull << remn1) - 1ull));
      u64 act0 = vm0 & ~remb0;                   // SGPR
      u64 act1 = vm1 & ~remb1;                   // SGPR

      // ---- word0: ballot-round greedy fixpoint
      u64 U = act0, K0 = 0;
      while (U) {
        u64 covered = __ballot((cA & U) != 0ull);
        u64 nk = U & ~covered;                   // definite keepers
        u64 supp = __ballot((cA & nk) != 0ull);  // definitely suppressed
        K0 |= nk;
        U &= ~(nk | supp);
      }
      u64 kw0 = K0;

      // ---- word1: remove word0-keeper suppression (one ballot), then scan
      u64 s01 = __ballot((cB & kw0) != 0ull);
      u64 U1 = act1 & ~s01, K1 = 0;
      while (U1) {
        u64 covered = __ballot((cC & U1) != 0ull);
        u64 nk = U1 & ~covered;
        u64 supp = __ballot((cC & nk) != 0ull);
        K1 |= nk;
        U1 &= ~(nk | supp);
      }
      u64 kw1 = K1;

      if (lane == 0) { keepw[b0] = kw0; keepw[b1] = kw1; }

      // ---- carries: words b0,b1 -> cols b0+2..b0+5 (4 ballots)
      u64 f2 = __ballot(((cD0 & kw0) | (cD1 & kw1)) != 0ull);
      u64 f3 = __ballot(((cE0 & kw0) | (cE1 & kw1)) != 0ull);
      u64 f4 = __ballot(((cF0 & kw0) | (cF1 & kw1)) != 0ull);
      u64 f5 = __ballot(((cG0 & kw0) | (cG1 & kw1)) != 0ull);
      p0c = f2; p1c = f3;                        // land at T+1
      q0c = qn0; q1c = qn1;                      // land at T+1 (from T-1)
      qn0 = f4; qn1 = f5;                        // land at T+2
      __builtin_amdgcn_s_setprio(0);             // yield while others consume
    } else {
      // ---- consume tiles issued at T-1 (word-pair 2(T-2)), keeper-filtered
      // at load time — OR loop is mask-free (non-keeper rows loaded as 0).
      if (T >= 2) {
        int u = T - 2;
        int base = 2 * u + 6;
        if (base < VB) {
          u64 acc = 0;
          #pragma unroll
          for (int r = 0; r < 19; ++r) acc |= tl[r];
          int cL = base + lane;
          if (cL < VB && acc) atomicOr((unsigned long long*)&rem[cL], acc);
          if (base + 64 < VB) {                  // H half exists at all?
            u64 acc2 = 0;
            #pragma unroll
            for (int r = 0; r < 19; ++r) acc2 |= th[r];
            int cH = base + 64 + lane;
            if (cH < VB && acc2) atomicOr((unsigned long long*)&rem[cH], acc2);
          }
        }
      }
      // ---- issue keeper-filtered tiles for word-pair 2(T-1); keepw was
      // published at iter T-1, read post-barrier. Consumed at T+1.
      if (T >= 1 && T + 1 < NT) {
        int u = T - 1;
        int base = 2 * u + 6;
        if (base < VB) {
          u64 kws0 = rfl64(keepw[2 * u]);        // broadcast read
          u64 kws1 = rfl64(keepw[2 * u + 1]);
          int cL = base + lane;
          bool okL = (cL < VB);
          // rows 128u+rs..+18: u <= NT-3 -> row <= 128*(NT-3)+127 < 8400
          const u64* pr = mask + (u64)(128 * u + rs) * CBLK;
          #pragma unroll
          for (int r = 0; r < 19; ++r) {
            int rr = rs + r;                     // wave-uniform
            u64 kb = (rr < 64) ? (kws0 >> rr) : (kws1 >> (rr - 64));
            bool rok = (r < nr) && ((kb & 1ull) != 0ull);
            tl[r] = (rok && okL) ? pr[(u64)r * CBLK + cL] : 0ull;
          }
          if (base + 64 < VB) {
            int cH = cL + 64;
            bool okH = (cH < VB);
            #pragma unroll
            for (int r = 0; r < 19; ++r) {
              int rr = rs + r;
              u64 kb = (rr < 64) ? (kws0 >> rr) : (kws1 >> (rr - 64));
              bool rok = (r < nr) && ((kb & 1ull) != 0ull);
              th[r] = (rok && okH) ? pr[(u64)r * CBLK + cH] : 0ull;
            }
          }
        }
      }
    }
  }
  __syncthreads();

  // ---- fused masked output (512 threads)
  for (int r2 = tid; r2 < N_ANCH; r2 += 512) {
    u64 kv = keepw[r2 >> 6];
    bool kp = (kv >> (r2 & 63)) & 1ull;
    float4 b4 = sbox[r2];
    float sc = sscore[r2];
    float* o = out + r2 * 5;
    o[0] = kp ? b4.x : 0.f;
    o[1] = kp ? b4.y : 0.f;
    o[2] = kp ? b4.z : 0.f;
    o[3] = kp ? b4.w : 0.f;
    o[4] = kp ? sc : 0.f;
  }
}

extern "C" void kernel_launch(void* const* d_in, const int* in_sizes, int n_in,
                              void* d_out, int out_size, void* d_ws, size_t ws_size,
                              hipStream_t stream) {
  const float* raw = (const float*)d_in[0];
  float* out = (float*)d_out;
  char* ws = (char*)d_ws;
  // ws layout: sbox (8448*16 B) | sscore (8448*4 B) | mask (8400*132*8 B) ≈ 9.04 MB
  float4* sbox = (float4*)ws;
  float* sscore = (float*)(ws + 8448 * 16);
  u64* mask = (u64*)(ws + 8448 * 16 + 8448 * 4);

  rank_kernel<<<2100, 256, 0, stream>>>(raw, sbox, sscore);
  mask_kernel<<<dim3(CBLK, 33), 256, 0, stream>>>(sbox, sscore, mask);
  nms_kernel<<<1, 512, 0, stream>>>(sbox, sscore, mask, out);
}